// Round 6
// baseline (192.706 us; speedup 1.0000x reference)
//
#include <hip/hip_runtime.h>

#define N_NODES 50000
#define N_EDGES 800000
#define DIM 128
#define NEG_SLOPE 0.01f
#define CAP 32           // bucket capacity; eidx = 3.2 MB -> per-XCD-L2-resident
#define OVF_MAX 4096     // overflow list capacity (expected usage: tens)

// ---- bf16 pack/unpack (RNE) ----
__device__ inline unsigned f2b_rne2(float a, float b) {
    unsigned ua = __float_as_uint(a), ub = __float_as_uint(b);
    ua = (ua + 0x7fffu + ((ua >> 16) & 1u)) >> 16;
    ub = (ub + 0x7fffu + ((ub >> 16) & 1u)) >> 16;
    return ua | (ub << 16);
}
__device__ inline float b2f_lo(unsigned u) { return __uint_as_float(u << 16); }
__device__ inline float b2f_hi(unsigned u) { return __uint_as_float(u & 0xffff0000u); }

// ---------------- single-pass bucket build + degrees (2 edges/thread) ----------------
__global__ void k_fillbucket(const int* __restrict__ src, const int* __restrict__ dst,
                             int* __restrict__ ocnt, int* __restrict__ icnt,
                             unsigned short* __restrict__ eidx,
                             int* __restrict__ ovf_cnt, int2* __restrict__ ovf, int ne2) {
    int t = blockIdx.x * blockDim.x + threadIdx.x;
    if (t >= ne2) return;
    int2 s = ((const int2*)src)[t];
    int2 d = ((const int2*)dst)[t];
    atomicAdd(&ocnt[s.x], 1);
    atomicAdd(&ocnt[s.y], 1);
    int p0 = atomicAdd(&icnt[d.x], 1);
    if (p0 < CAP) eidx[d.x * CAP + p0] = (unsigned short)s.x;
    else { int o = atomicAdd(ovf_cnt, 1); if (o < OVF_MAX) ovf[o] = make_int2(d.x, s.x); }
    int p1 = atomicAdd(&icnt[d.y], 1);
    if (p1 < CAP) eidx[d.y * CAP + p1] = (unsigned short)s.y;
    else { int o = atomicAdd(ovf_cnt, 1); if (o < OVF_MAX) ovf[o] = make_int2(d.y, s.y); }
}

// ---------------- per-node prep ----------------
__global__ void k_prep(const float* __restrict__ weight, const int* __restrict__ sig,
                       const float* __restrict__ emb,
                       const int* __restrict__ ocnt, const int* __restrict__ icnt,
                       float* __restrict__ oinv, float* __restrict__ iinv,
                       float* __restrict__ feats3, int n) {
    int i = blockIdx.x * blockDim.x + threadIdx.x;
    if (i < n) {
        float od = (float)max(ocnt[i], 1);
        float id = (float)max(icnt[i], 1);
        float oi = 1.0f / sqrtf(od);
        oinv[i] = oi;
        iinv[i] = 1.0f / sqrtf(id);
        int s = sig[i];
        feats3[i * 3 + 0] = weight[i] * oi;
        feats3[i * 3 + 1] = emb[s * 2 + 0] * oi;
        feats3[i * 3 + 2] = emb[s * 2 + 1] * oi;
    }
}

// ---------------- layer-1 overflow patch: agg3ovf[dst] += feats3[src] ----------------
__global__ void k_ovf3(const int* __restrict__ ovf_cnt, const int2* __restrict__ ovf,
                       const float* __restrict__ feats3, float* __restrict__ agg3ovf) {
    int t = blockIdx.x * blockDim.x + threadIdx.x;
    int cnt = min(*ovf_cnt, OVF_MAX);
    if (t >= cnt) return;
    int2 e = ovf[t];                           // (dst, src)
    atomicAdd(&agg3ovf[e.x * 3 + 0], feats3[e.y * 3 + 0]);
    atomicAdd(&agg3ovf[e.x * 3 + 1], feats3[e.y * 3 + 1]);
    atomicAdd(&agg3ovf[e.x * 3 + 2], feats3[e.y * 3 + 2]);
}

// ---------------- fused layer-1: agg3 gather + (.@W0+b0) + lrelu + bf16 pack ----------------
// 32 lanes per node; lane q computes output cols 4q..4q+3.
__global__ void k_aggl1(const int* __restrict__ icnt, const unsigned short* __restrict__ eidx,
                        const float* __restrict__ feats3, const float* __restrict__ agg3ovf,
                        const float* __restrict__ iinv, const float* __restrict__ oinv,
                        const float* __restrict__ W0, const float* __restrict__ b0,
                        unsigned* __restrict__ hs, int n) {
    int t = blockIdx.x * blockDim.x + threadIdx.x;
    int i = t >> 5;
    if (i >= n) return;
    int q = t & 31;
    int deg = min(icnt[i], CAP);
    const unsigned short* row = eidx + i * CAP;
    float a0 = 0.f, a1 = 0.f, a2 = 0.f;
    for (int k = q; k < deg; k += 32) {
        int s = row[k];
        a0 += feats3[s * 3 + 0];
        a1 += feats3[s * 3 + 1];
        a2 += feats3[s * 3 + 2];
    }
    // 32-lane butterfly reduce (masks <=16 stay within the 32-lane group)
    #pragma unroll
    for (int m = 1; m <= 16; m <<= 1) {
        a0 += __shfl_xor(a0, m);
        a1 += __shfl_xor(a1, m);
        a2 += __shfl_xor(a2, m);
    }
    // overflow-edge contributions (zero for all but a handful of nodes)
    a0 += agg3ovf[i * 3 + 0];
    a1 += agg3ovf[i * 3 + 1];
    a2 += agg3ovf[i * 3 + 2];
    float ii = iinv[i], oi = oinv[i];
    a0 *= ii; a1 *= ii; a2 *= ii;
    int j0 = q * 4;
    float4 w0r = *(const float4*)&W0[0 * DIM + j0];
    float4 w1r = *(const float4*)&W0[1 * DIM + j0];
    float4 w2r = *(const float4*)&W0[2 * DIM + j0];
    float4 bb  = *(const float4*)&b0[j0];
    float v0 = a0 * w0r.x + a1 * w1r.x + a2 * w2r.x + bb.x;
    float v1 = a0 * w0r.y + a1 * w1r.y + a2 * w2r.y + bb.y;
    float v2 = a0 * w0r.z + a1 * w1r.z + a2 * w2r.z + bb.z;
    float v3 = a0 * w0r.w + a1 * w1r.w + a2 * w2r.w + bb.w;
    v0 = v0 > 0.f ? v0 : NEG_SLOPE * v0;
    v1 = v1 > 0.f ? v1 : NEG_SLOPE * v1;
    v2 = v2 > 0.f ? v2 : NEG_SLOPE * v2;
    v3 = v3 > 0.f ? v3 : NEG_SLOPE * v3;
    ((uint2*)hs)[i * 32 + q] = make_uint2(f2b_rne2(v0 * oi, v1 * oi),
                                          f2b_rne2(v2 * oi, v3 * oi));
}

// ---------------- layer-2 aggregation: bucket gather, 32 threads/node ----------------
__global__ void k_gather128(const int* __restrict__ icnt, const unsigned short* __restrict__ eidx,
                            const unsigned* __restrict__ hs, float* __restrict__ out, int n) {
    int t = blockIdx.x * blockDim.x + threadIdx.x;
    int i = t >> 5;
    if (i >= n) return;
    int q = t & 31;
    int deg = min(icnt[i], CAP);
    const unsigned short* row = eidx + i * CAP;
    const uint2* hs2 = (const uint2*)hs;
    float a0 = 0.f, a1 = 0.f, a2 = 0.f, a3 = 0.f;
    int k = 0;
    for (; k + 2 <= deg; k += 2) {
        int s0 = row[k], s1 = row[k + 1];
        uint2 u0 = hs2[s0 * 32 + q];
        uint2 u1 = hs2[s1 * 32 + q];
        a0 += b2f_lo(u0.x) + b2f_lo(u1.x);
        a1 += b2f_hi(u0.x) + b2f_hi(u1.x);
        a2 += b2f_lo(u0.y) + b2f_lo(u1.y);
        a3 += b2f_hi(u0.y) + b2f_hi(u1.y);
    }
    if (k < deg) {
        int s = row[k];
        uint2 u = hs2[s * 32 + q];
        a0 += b2f_lo(u.x); a1 += b2f_hi(u.x);
        a2 += b2f_lo(u.y); a3 += b2f_hi(u.y);
    }
    ((float4*)out)[i * 32 + q] = make_float4(a0, a1, a2, a3);
}

// ---------------- layer-2 overflow edges: atomic add into out ----------------
__global__ void k_overflow(const int* __restrict__ ovf_cnt, const int2* __restrict__ ovf,
                           const unsigned* __restrict__ hs, float* __restrict__ out) {
    int g = blockIdx.x * blockDim.x + threadIdx.x;
    int entry = g >> 5, q = g & 31;
    int cnt = min(*ovf_cnt, OVF_MAX);
    if (entry >= cnt) return;
    int2 e = ovf[entry];                       // (dst, src)
    uint2 u = ((const uint2*)hs)[e.y * 32 + q];
    float* o = out + (size_t)e.x * DIM + q * 4;
    atomicAdd(o + 0, b2f_lo(u.x));
    atomicAdd(o + 1, b2f_hi(u.x));
    atomicAdd(o + 2, b2f_lo(u.y));
    atomicAdd(o + 3, b2f_hi(u.y));
}

// ---------------- final: out = (out * iinv) @ W1 + b1, 8x8 register tile ----------------
#define FB_NODES 128
__global__ __launch_bounds__(256) void k_final(const float* __restrict__ iinv,
                                               const float* __restrict__ W1,
                                               const float* __restrict__ b1,
                                               float* __restrict__ out, int n) {
    __shared__ float sW[DIM * DIM];        // 64 KB
    __shared__ float sA[FB_NODES * DIM];   // 64 KB
    int tid = threadIdx.x;
    int base = blockIdx.x * FB_NODES;

    for (int i = tid; i < DIM * DIM / 4; i += 256)
        ((float4*)sW)[i] = ((const float4*)W1)[i];
    for (int i = tid; i < FB_NODES * DIM / 4; i += 256) {
        int r = i >> 5;
        int nIdx = base + r;
        float4 v = make_float4(0.f, 0.f, 0.f, 0.f);
        if (nIdx < n) {
            v = ((const float4*)out)[(size_t)nIdx * 32 + (i & 31)];
            float ii = iinv[nIdx];
            v.x *= ii; v.y *= ii; v.z *= ii; v.w *= ii;
        }
        ((float4*)sA)[i] = v;
    }

    int cg = tid & 15, ng = tid >> 4;
    int col0 = cg * 8, row0 = ng * 8;

    float bb[8];
    #pragma unroll
    for (int j = 0; j < 8; ++j) bb[j] = b1[col0 + j];

    float acc[8][8];
    #pragma unroll
    for (int i = 0; i < 8; ++i)
        #pragma unroll
        for (int j = 0; j < 8; ++j) acc[i][j] = 0.f;

    __syncthreads();

    for (int k = 0; k < DIM; k += 4) {
        float4 a[8];
        #pragma unroll
        for (int i = 0; i < 8; ++i)
            a[i] = *(const float4*)&sA[(row0 + i) * DIM + k];
        #pragma unroll
        for (int kk = 0; kk < 4; ++kk) {
            float4 w0 = *(const float4*)&sW[(k + kk) * DIM + col0];
            float4 w1v = *(const float4*)&sW[(k + kk) * DIM + col0 + 4];
            #pragma unroll
            for (int i = 0; i < 8; ++i) {
                float av = (kk == 0) ? a[i].x : (kk == 1) ? a[i].y : (kk == 2) ? a[i].z : a[i].w;
                acc[i][0] += av * w0.x;  acc[i][1] += av * w0.y;
                acc[i][2] += av * w0.z;  acc[i][3] += av * w0.w;
                acc[i][4] += av * w1v.x; acc[i][5] += av * w1v.y;
                acc[i][6] += av * w1v.z; acc[i][7] += av * w1v.w;
            }
        }
    }

    #pragma unroll
    for (int i = 0; i < 8; ++i) {
        int nIdx = base + row0 + i;
        if (nIdx < n) {
            float4 o0, o1;
            o0.x = acc[i][0] + bb[0]; o0.y = acc[i][1] + bb[1];
            o0.z = acc[i][2] + bb[2]; o0.w = acc[i][3] + bb[3];
            o1.x = acc[i][4] + bb[4]; o1.y = acc[i][5] + bb[5];
            o1.z = acc[i][6] + bb[6]; o1.w = acc[i][7] + bb[7];
            ((float4*)out)[(size_t)nIdx * 32 + (col0 >> 2)] = o0;
            ((float4*)out)[(size_t)nIdx * 32 + (col0 >> 2) + 1] = o1;
        }
    }
}

// ---------------- launch ----------------
extern "C" void kernel_launch(void* const* d_in, const int* in_sizes, int n_in,
                              void* d_out, int out_size, void* d_ws, size_t ws_size,
                              hipStream_t stream) {
    const int*   src  = (const int*)d_in[0];
    const int*   dst  = (const int*)d_in[1];
    const float* weight = (const float*)d_in[2];
    const int*   sig  = (const int*)d_in[3];
    const float* emb  = (const float*)d_in[4];
    const float* W0   = (const float*)d_in[5];
    const float* b0   = (const float*)d_in[6];
    const float* W1   = (const float*)d_in[7];
    const float* b1   = (const float*)d_in[8];
    float* out = (float*)d_out;

    // ---- workspace layout (4B words); zeroed buffers first ----
    int*   ocnt    = (int*)d_ws;                          // @0        50000 (memset)
    int*   icnt    = ocnt + N_NODES;                      // @50000    50000 (memset)
    int*   ovf_cnt = icnt + N_NODES;                      // @100000   8     (memset)
    float* agg3ovf = (float*)(ovf_cnt + 8);               // @100008   150000 (memset)
    int2*  ovf     = (int2*)(agg3ovf + 3 * N_NODES);      // @250008   4096 int2 (byte 1000032 %8==0)
    float* oinv    = (float*)(ovf + OVF_MAX);             // @258200   50000
    float* iinv    = oinv + N_NODES;                      // @308200   50000
    float* feats3  = iinv + N_NODES;                      // @358200   150000
    unsigned short* eidx = (unsigned short*)(feats3 + 3 * N_NODES); // @508200: 1.6M ushort
    unsigned* hs   = (unsigned*)(eidx + (size_t)N_NODES * CAP);     // @1308200 (byte %8==0)

    hipMemsetAsync(d_ws, 0, (size_t)(2 * N_NODES + 8 + 3 * N_NODES) * 4, stream);

    k_fillbucket<<<(N_EDGES / 2 + 255) / 256, 256, 0, stream>>>(src, dst, ocnt, icnt, eidx,
                                                                ovf_cnt, ovf, N_EDGES / 2);
    k_prep<<<(N_NODES + 255) / 256, 256, 0, stream>>>(weight, sig, emb, ocnt, icnt,
                                                      oinv, iinv, feats3, N_NODES);
    k_ovf3<<<(OVF_MAX + 255) / 256, 256, 0, stream>>>(ovf_cnt, ovf, feats3, agg3ovf);
    k_aggl1<<<(N_NODES * 32 + 255) / 256, 256, 0, stream>>>(icnt, eidx, feats3, agg3ovf,
                                                            iinv, oinv, W0, b0, hs, N_NODES);
    k_gather128<<<((N_NODES * 32) + 255) / 256, 256, 0, stream>>>(icnt, eidx, hs, out, N_NODES);
    k_overflow<<<(OVF_MAX * 32) / 256, 256, 0, stream>>>(ovf_cnt, ovf, hs, out);
    k_final<<<(N_NODES + FB_NODES - 1) / FB_NODES, 256, 0, stream>>>(iinv, W1, b1, out, N_NODES);
}

// Round 7
// 172.108 us; speedup vs baseline: 1.1197x; 1.1197x over previous
//
#include <hip/hip_runtime.h>

#define N_NODES 50000
#define N_EDGES 800000
#define DIM 128
#define NEG_SLOPE 0.01f
#define CAP 32           // bucket capacity
#define OVF_MAX 4096     // overflow list capacity (expected usage: tens)

// ---- out-degree histogram partitioning ----
#define NR 4             // node ranges
#define RNODES 12512     // nodes per range (4*12512 = 50048 >= 50000), LDS 50 KB
#define SLICES 64        // edge slices per range
#define ESLICE (N_EDGES / SLICES)   // 12500 edges per slice

// ---- bf16 pack/unpack (RNE) ----
__device__ inline unsigned f2b_rne2(float a, float b) {
    unsigned ua = __float_as_uint(a), ub = __float_as_uint(b);
    ua = (ua + 0x7fffu + ((ua >> 16) & 1u)) >> 16;
    ub = (ub + 0x7fffu + ((ub >> 16) & 1u)) >> 16;
    return ua | (ub << 16);
}
__device__ inline float b2f_lo(unsigned u) { return __uint_as_float(u << 16); }
__device__ inline float b2f_hi(unsigned u) { return __uint_as_float(u & 0xffff0000u); }

// ---------------- bucket build: 1 atomic/edge (icnt doubles as cursor) ----------------
__global__ void k_fillbucket(const int* __restrict__ src, const int* __restrict__ dst,
                             int* __restrict__ icnt,
                             unsigned short* __restrict__ eidx,
                             int* __restrict__ ovf_cnt, int2* __restrict__ ovf, int ne2) {
    int t = blockIdx.x * blockDim.x + threadIdx.x;
    if (t >= ne2) return;
    int2 s = ((const int2*)src)[t];
    int2 d = ((const int2*)dst)[t];
    int p0 = atomicAdd(&icnt[d.x], 1);
    if (p0 < CAP) eidx[d.x * CAP + p0] = (unsigned short)s.x;
    else { int o = atomicAdd(ovf_cnt, 1); if (o < OVF_MAX) ovf[o] = make_int2(d.x, s.x); }
    int p1 = atomicAdd(&icnt[d.y], 1);
    if (p1 < CAP) eidx[d.y * CAP + p1] = (unsigned short)s.y;
    else { int o = atomicAdd(ovf_cnt, 1); if (o < OVF_MAX) ovf[o] = make_int2(d.y, s.y); }
}

// ---------------- out-degree histogram: LDS-privatized, range x slice ----------------
// blockIdx.x = range*SLICES + slice. Each block histograms its edge slice for its
// node range in LDS, then flushes with plain coalesced stores (no global atomics).
__global__ __launch_bounds__(256) void k_hist(const int* __restrict__ src,
                                              int* __restrict__ partial) {
    __shared__ int bins[RNODES];           // 50 KB
    int range = blockIdx.x / SLICES;
    int slice = blockIdx.x % SLICES;
    int tid = threadIdx.x;
    for (int j = tid; j < RNODES; j += 256) bins[j] = 0;
    __syncthreads();
    int base_node = range * RNODES;
    const int4* src4 = (const int4*)(src + slice * ESLICE);
    for (int t = tid; t < ESLICE / 4; t += 256) {
        int4 v = src4[t];
        unsigned u0 = (unsigned)(v.x - base_node);
        unsigned u1 = (unsigned)(v.y - base_node);
        unsigned u2 = (unsigned)(v.z - base_node);
        unsigned u3 = (unsigned)(v.w - base_node);
        if (u0 < RNODES) atomicAdd(&bins[u0], 1);
        if (u1 < RNODES) atomicAdd(&bins[u1], 1);
        if (u2 < RNODES) atomicAdd(&bins[u2], 1);
        if (u3 < RNODES) atomicAdd(&bins[u3], 1);
    }
    __syncthreads();
    int* outp = partial + (size_t)blockIdx.x * RNODES;
    for (int j = tid; j < RNODES; j += 256) outp[j] = bins[j];
}

// ---------------- per-node prep (sums out-degree partials inline) ----------------
__global__ void k_prep(const float* __restrict__ weight, const int* __restrict__ sig,
                       const float* __restrict__ emb,
                       const int* __restrict__ partial, const int* __restrict__ icnt,
                       float* __restrict__ oinv, float* __restrict__ iinv,
                       float* __restrict__ feats3, int n) {
    int i = blockIdx.x * blockDim.x + threadIdx.x;
    if (i >= n) return;
    int range = i / RNODES, off = i % RNODES;
    const int* p = partial + ((size_t)range * SLICES) * RNODES + off;
    int od = 0;
    #pragma unroll 8
    for (int s = 0; s < SLICES; ++s) od += p[(size_t)s * RNODES];
    float odf = (float)max(od, 1);
    float idf = (float)max(icnt[i], 1);
    float oi = 1.0f / sqrtf(odf);
    oinv[i] = oi;
    iinv[i] = 1.0f / sqrtf(idf);
    int sg = sig[i];
    feats3[i * 3 + 0] = weight[i] * oi;
    feats3[i * 3 + 1] = emb[sg * 2 + 0] * oi;
    feats3[i * 3 + 2] = emb[sg * 2 + 1] * oi;
}

// ---------------- layer-1 overflow patch: agg3ovf[dst] += feats3[src] ----------------
__global__ void k_ovf3(const int* __restrict__ ovf_cnt, const int2* __restrict__ ovf,
                       const float* __restrict__ feats3, float* __restrict__ agg3ovf) {
    int t = blockIdx.x * blockDim.x + threadIdx.x;
    int cnt = min(*ovf_cnt, OVF_MAX);
    if (t >= cnt) return;
    int2 e = ovf[t];                           // (dst, src)
    atomicAdd(&agg3ovf[e.x * 3 + 0], feats3[e.y * 3 + 0]);
    atomicAdd(&agg3ovf[e.x * 3 + 1], feats3[e.y * 3 + 1]);
    atomicAdd(&agg3ovf[e.x * 3 + 2], feats3[e.y * 3 + 2]);
}

// ---------------- fused layer-1: agg3 gather + (.@W0+b0) + lrelu + bf16 pack ----------------
__global__ void k_aggl1(const int* __restrict__ icnt, const unsigned short* __restrict__ eidx,
                        const float* __restrict__ feats3, const float* __restrict__ agg3ovf,
                        const float* __restrict__ iinv, const float* __restrict__ oinv,
                        const float* __restrict__ W0, const float* __restrict__ b0,
                        unsigned* __restrict__ hs, int n) {
    int t = blockIdx.x * blockDim.x + threadIdx.x;
    int i = t >> 5;
    if (i >= n) return;
    int q = t & 31;
    int deg = min(icnt[i], CAP);
    const unsigned short* row = eidx + i * CAP;
    float a0 = 0.f, a1 = 0.f, a2 = 0.f;
    for (int k = q; k < deg; k += 32) {
        int s = row[k];
        a0 += feats3[s * 3 + 0];
        a1 += feats3[s * 3 + 1];
        a2 += feats3[s * 3 + 2];
    }
    #pragma unroll
    for (int m = 1; m <= 16; m <<= 1) {
        a0 += __shfl_xor(a0, m);
        a1 += __shfl_xor(a1, m);
        a2 += __shfl_xor(a2, m);
    }
    a0 += agg3ovf[i * 3 + 0];
    a1 += agg3ovf[i * 3 + 1];
    a2 += agg3ovf[i * 3 + 2];
    float ii = iinv[i], oi = oinv[i];
    a0 *= ii; a1 *= ii; a2 *= ii;
    int j0 = q * 4;
    float4 w0r = *(const float4*)&W0[0 * DIM + j0];
    float4 w1r = *(const float4*)&W0[1 * DIM + j0];
    float4 w2r = *(const float4*)&W0[2 * DIM + j0];
    float4 bb  = *(const float4*)&b0[j0];
    float v0 = a0 * w0r.x + a1 * w1r.x + a2 * w2r.x + bb.x;
    float v1 = a0 * w0r.y + a1 * w1r.y + a2 * w2r.y + bb.y;
    float v2 = a0 * w0r.z + a1 * w1r.z + a2 * w2r.z + bb.z;
    float v3 = a0 * w0r.w + a1 * w1r.w + a2 * w2r.w + bb.w;
    v0 = v0 > 0.f ? v0 : NEG_SLOPE * v0;
    v1 = v1 > 0.f ? v1 : NEG_SLOPE * v1;
    v2 = v2 > 0.f ? v2 : NEG_SLOPE * v2;
    v3 = v3 > 0.f ? v3 : NEG_SLOPE * v3;
    ((uint2*)hs)[i * 32 + q] = make_uint2(f2b_rne2(v0 * oi, v1 * oi),
                                          f2b_rne2(v2 * oi, v3 * oi));
}

// ---------------- layer-2 aggregation: bucket gather, 32 threads/node ----------------
__global__ void k_gather128(const int* __restrict__ icnt, const unsigned short* __restrict__ eidx,
                            const unsigned* __restrict__ hs, float* __restrict__ out, int n) {
    int t = blockIdx.x * blockDim.x + threadIdx.x;
    int i = t >> 5;
    if (i >= n) return;
    int q = t & 31;
    int deg = min(icnt[i], CAP);
    const unsigned short* row = eidx + i * CAP;
    const uint2* hs2 = (const uint2*)hs;
    float a0 = 0.f, a1 = 0.f, a2 = 0.f, a3 = 0.f;
    int k = 0;
    for (; k + 2 <= deg; k += 2) {
        int s0 = row[k], s1 = row[k + 1];
        uint2 u0 = hs2[s0 * 32 + q];
        uint2 u1 = hs2[s1 * 32 + q];
        a0 += b2f_lo(u0.x) + b2f_lo(u1.x);
        a1 += b2f_hi(u0.x) + b2f_hi(u1.x);
        a2 += b2f_lo(u0.y) + b2f_lo(u1.y);
        a3 += b2f_hi(u0.y) + b2f_hi(u1.y);
    }
    if (k < deg) {
        int s = row[k];
        uint2 u = hs2[s * 32 + q];
        a0 += b2f_lo(u.x); a1 += b2f_hi(u.x);
        a2 += b2f_lo(u.y); a3 += b2f_hi(u.y);
    }
    ((float4*)out)[i * 32 + q] = make_float4(a0, a1, a2, a3);
}

// ---------------- layer-2 overflow edges: atomic add into out ----------------
__global__ void k_overflow(const int* __restrict__ ovf_cnt, const int2* __restrict__ ovf,
                           const unsigned* __restrict__ hs, float* __restrict__ out) {
    int g = blockIdx.x * blockDim.x + threadIdx.x;
    int entry = g >> 5, q = g & 31;
    int cnt = min(*ovf_cnt, OVF_MAX);
    if (entry >= cnt) return;
    int2 e = ovf[entry];                       // (dst, src)
    uint2 u = ((const uint2*)hs)[e.y * 32 + q];
    float* o = out + (size_t)e.x * DIM + q * 4;
    atomicAdd(o + 0, b2f_lo(u.x));
    atomicAdd(o + 1, b2f_hi(u.x));
    atomicAdd(o + 2, b2f_lo(u.y));
    atomicAdd(o + 3, b2f_hi(u.y));
}

// ---------------- final: out = (out * iinv) @ W1 + b1, 8x8 register tile ----------------
#define FB_NODES 128
__global__ __launch_bounds__(256) void k_final(const float* __restrict__ iinv,
                                               const float* __restrict__ W1,
                                               const float* __restrict__ b1,
                                               float* __restrict__ out, int n) {
    __shared__ float sW[DIM * DIM];        // 64 KB
    __shared__ float sA[FB_NODES * DIM];   // 64 KB
    int tid = threadIdx.x;
    int base = blockIdx.x * FB_NODES;

    for (int i = tid; i < DIM * DIM / 4; i += 256)
        ((float4*)sW)[i] = ((const float4*)W1)[i];
    for (int i = tid; i < FB_NODES * DIM / 4; i += 256) {
        int r = i >> 5;
        int nIdx = base + r;
        float4 v = make_float4(0.f, 0.f, 0.f, 0.f);
        if (nIdx < n) {
            v = ((const float4*)out)[(size_t)nIdx * 32 + (i & 31)];
            float ii = iinv[nIdx];
            v.x *= ii; v.y *= ii; v.z *= ii; v.w *= ii;
        }
        ((float4*)sA)[i] = v;
    }

    int cg = tid & 15, ng = tid >> 4;
    int col0 = cg * 8, row0 = ng * 8;

    float bb[8];
    #pragma unroll
    for (int j = 0; j < 8; ++j) bb[j] = b1[col0 + j];

    float acc[8][8];
    #pragma unroll
    for (int i = 0; i < 8; ++i)
        #pragma unroll
        for (int j = 0; j < 8; ++j) acc[i][j] = 0.f;

    __syncthreads();

    for (int k = 0; k < DIM; k += 4) {
        float4 a[8];
        #pragma unroll
        for (int i = 0; i < 8; ++i)
            a[i] = *(const float4*)&sA[(row0 + i) * DIM + k];
        #pragma unroll
        for (int kk = 0; kk < 4; ++kk) {
            float4 w0 = *(const float4*)&sW[(k + kk) * DIM + col0];
            float4 w1v = *(const float4*)&sW[(k + kk) * DIM + col0 + 4];
            #pragma unroll
            for (int i = 0; i < 8; ++i) {
                float av = (kk == 0) ? a[i].x : (kk == 1) ? a[i].y : (kk == 2) ? a[i].z : a[i].w;
                acc[i][0] += av * w0.x;  acc[i][1] += av * w0.y;
                acc[i][2] += av * w0.z;  acc[i][3] += av * w0.w;
                acc[i][4] += av * w1v.x; acc[i][5] += av * w1v.y;
                acc[i][6] += av * w1v.z; acc[i][7] += av * w1v.w;
            }
        }
    }

    #pragma unroll
    for (int i = 0; i < 8; ++i) {
        int nIdx = base + row0 + i;
        if (nIdx < n) {
            float4 o0, o1;
            o0.x = acc[i][0] + bb[0]; o0.y = acc[i][1] + bb[1];
            o0.z = acc[i][2] + bb[2]; o0.w = acc[i][3] + bb[3];
            o1.x = acc[i][4] + bb[4]; o1.y = acc[i][5] + bb[5];
            o1.z = acc[i][6] + bb[6]; o1.w = acc[i][7] + bb[7];
            ((float4*)out)[(size_t)nIdx * 32 + (col0 >> 2)] = o0;
            ((float4*)out)[(size_t)nIdx * 32 + (col0 >> 2) + 1] = o1;
        }
    }
}

// ---------------- launch ----------------
extern "C" void kernel_launch(void* const* d_in, const int* in_sizes, int n_in,
                              void* d_out, int out_size, void* d_ws, size_t ws_size,
                              hipStream_t stream) {
    const int*   src  = (const int*)d_in[0];
    const int*   dst  = (const int*)d_in[1];
    const float* weight = (const float*)d_in[2];
    const int*   sig  = (const int*)d_in[3];
    const float* emb  = (const float*)d_in[4];
    const float* W0   = (const float*)d_in[5];
    const float* b0   = (const float*)d_in[6];
    const float* W1   = (const float*)d_in[7];
    const float* b1   = (const float*)d_in[8];
    float* out = (float*)d_out;

    // ---- workspace layout (4B words); zeroed buffers first ----
    int*   icnt    = (int*)d_ws;                          // @0        50000 (memset)
    int*   ovf_cnt = icnt + N_NODES;                      // @50000    8     (memset)
    float* agg3ovf = (float*)(ovf_cnt + 8);               // @50008    150000 (memset)
    int2*  ovf     = (int2*)(agg3ovf + 3 * N_NODES);      // @200008   4096 int2 (byte %8==0)
    float* oinv    = (float*)(ovf + OVF_MAX);             // @208200   50000
    float* iinv    = oinv + N_NODES;                      // @258200   50000
    float* feats3  = iinv + N_NODES;                      // @308200   150000
    int*   partial = feats3 + 3 * N_NODES ? (int*)(feats3 + 3 * N_NODES) : nullptr; // @458200
    unsigned short* eidx = (unsigned short*)(partial + (size_t)NR * SLICES * RNODES); // @3661272w
    unsigned* hs   = (unsigned*)(eidx + (size_t)N_NODES * CAP);     // +800000 w (byte %8==0)

    hipMemsetAsync(d_ws, 0, (size_t)(N_NODES + 8 + 3 * N_NODES) * 4, stream);

    k_fillbucket<<<(N_EDGES / 2 + 255) / 256, 256, 0, stream>>>(src, dst, icnt, eidx,
                                                                ovf_cnt, ovf, N_EDGES / 2);
    k_hist<<<NR * SLICES, 256, 0, stream>>>(src, partial);
    k_prep<<<(N_NODES + 255) / 256, 256, 0, stream>>>(weight, sig, emb, partial, icnt,
                                                      oinv, iinv, feats3, N_NODES);
    k_ovf3<<<(OVF_MAX + 255) / 256, 256, 0, stream>>>(ovf_cnt, ovf, feats3, agg3ovf);
    k_aggl1<<<(N_NODES * 32 + 255) / 256, 256, 0, stream>>>(icnt, eidx, feats3, agg3ovf,
                                                            iinv, oinv, W0, b0, hs, N_NODES);
    k_gather128<<<((N_NODES * 32) + 255) / 256, 256, 0, stream>>>(icnt, eidx, hs, out, N_NODES);
    k_overflow<<<(OVF_MAX * 32) / 256, 256, 0, stream>>>(ovf_cnt, ovf, hs, out);
    k_final<<<(N_NODES + FB_NODES - 1) / FB_NODES, 256, 0, stream>>>(iinv, W1, b1, out, N_NODES);
}

// Round 8
// 161.846 us; speedup vs baseline: 1.1907x; 1.0634x over previous
//
#include <hip/hip_runtime.h>

#define N_NODES 50000
#define N_EDGES 800000
#define DIM 128
#define NEG_SLOPE 0.01f
#define CAP 32           // bucket capacity
#define OVF_MAX 4096     // overflow list capacity (expected usage: tens)

// ---- out-degree histogram partitioning ----
#define NR 4             // node ranges
#define RNODES 12512     // nodes per range (4*12512 = 50048 >= 50000), LDS 50 KB
#define SLICES 64        // edge slices per range
#define ESLICE (N_EDGES / SLICES)   // 12500 edges per slice

// ---- bf16 pack/unpack (RNE) ----
__device__ inline unsigned f2b_rne2(float a, float b) {
    unsigned ua = __float_as_uint(a), ub = __float_as_uint(b);
    ua = (ua + 0x7fffu + ((ua >> 16) & 1u)) >> 16;
    ub = (ub + 0x7fffu + ((ub >> 16) & 1u)) >> 16;
    return ua | (ub << 16);
}
__device__ inline float b2f_lo(unsigned u) { return __uint_as_float(u << 16); }
__device__ inline float b2f_hi(unsigned u) { return __uint_as_float(u & 0xffff0000u); }

// ---------------- bucket build: 1 atomic/edge (icnt doubles as cursor) ----------------
__global__ void k_fillbucket(const int* __restrict__ src, const int* __restrict__ dst,
                             int* __restrict__ icnt,
                             unsigned short* __restrict__ eidx,
                             int* __restrict__ ovf_cnt, int2* __restrict__ ovf, int ne2) {
    int t = blockIdx.x * blockDim.x + threadIdx.x;
    if (t >= ne2) return;
    int2 s = ((const int2*)src)[t];
    int2 d = ((const int2*)dst)[t];
    int p0 = atomicAdd(&icnt[d.x], 1);
    if (p0 < CAP) eidx[d.x * CAP + p0] = (unsigned short)s.x;
    else { int o = atomicAdd(ovf_cnt, 1); if (o < OVF_MAX) ovf[o] = make_int2(d.x, s.x); }
    int p1 = atomicAdd(&icnt[d.y], 1);
    if (p1 < CAP) eidx[d.y * CAP + p1] = (unsigned short)s.y;
    else { int o = atomicAdd(ovf_cnt, 1); if (o < OVF_MAX) ovf[o] = make_int2(d.y, s.y); }
}

// ---------------- out-degree histogram: LDS-privatized, range x slice ----------------
__global__ __launch_bounds__(256) void k_hist(const int* __restrict__ src,
                                              int* __restrict__ partial) {
    __shared__ int bins[RNODES];           // 50 KB
    int range = blockIdx.x / SLICES;
    int slice = blockIdx.x % SLICES;
    int tid = threadIdx.x;
    for (int j = tid; j < RNODES; j += 256) bins[j] = 0;
    __syncthreads();
    int base_node = range * RNODES;
    const int4* src4 = (const int4*)(src + slice * ESLICE);
    for (int t = tid; t < ESLICE / 4; t += 256) {
        int4 v = src4[t];
        unsigned u0 = (unsigned)(v.x - base_node);
        unsigned u1 = (unsigned)(v.y - base_node);
        unsigned u2 = (unsigned)(v.z - base_node);
        unsigned u3 = (unsigned)(v.w - base_node);
        if (u0 < RNODES) atomicAdd(&bins[u0], 1);
        if (u1 < RNODES) atomicAdd(&bins[u1], 1);
        if (u2 < RNODES) atomicAdd(&bins[u2], 1);
        if (u3 < RNODES) atomicAdd(&bins[u3], 1);
    }
    __syncthreads();
    int* outp = partial + (size_t)blockIdx.x * RNODES;
    for (int j = tid; j < RNODES; j += 256) outp[j] = bins[j];
}

// ---------------- per-node prep (sums out-degree partials inline) ----------------
__global__ void k_prep(const float* __restrict__ weight, const int* __restrict__ sig,
                       const float* __restrict__ emb,
                       const int* __restrict__ partial, const int* __restrict__ icnt,
                       float* __restrict__ oinv, float* __restrict__ iinv,
                       float* __restrict__ feats3, int n) {
    int i = blockIdx.x * blockDim.x + threadIdx.x;
    if (i >= n) return;
    int range = i / RNODES, off = i % RNODES;
    const int* p = partial + ((size_t)range * SLICES) * RNODES + off;
    int od = 0;
    #pragma unroll 8
    for (int s = 0; s < SLICES; ++s) od += p[(size_t)s * RNODES];
    float odf = (float)max(od, 1);
    float idf = (float)max(icnt[i], 1);
    float oi = 1.0f / sqrtf(odf);
    oinv[i] = oi;
    iinv[i] = 1.0f / sqrtf(idf);
    int sg = sig[i];
    feats3[i * 3 + 0] = weight[i] * oi;
    feats3[i * 3 + 1] = emb[sg * 2 + 0] * oi;
    feats3[i * 3 + 2] = emb[sg * 2 + 1] * oi;
}

// ---------------- layer-1 overflow patch: agg3ovf[dst] += feats3[src] ----------------
__global__ void k_ovf3(const int* __restrict__ ovf_cnt, const int2* __restrict__ ovf,
                       const float* __restrict__ feats3, float* __restrict__ agg3ovf) {
    int t = blockIdx.x * blockDim.x + threadIdx.x;
    int cnt = min(*ovf_cnt, OVF_MAX);
    if (t >= cnt) return;
    int2 e = ovf[t];                           // (dst, src)
    atomicAdd(&agg3ovf[e.x * 3 + 0], feats3[e.y * 3 + 0]);
    atomicAdd(&agg3ovf[e.x * 3 + 1], feats3[e.y * 3 + 1]);
    atomicAdd(&agg3ovf[e.x * 3 + 2], feats3[e.y * 3 + 2]);
}

// ---------------- fused layer-1: agg3 gather + (.@W0+b0) + lrelu + bf16 pack ----------------
__global__ void k_aggl1(const int* __restrict__ icnt, const unsigned short* __restrict__ eidx,
                        const float* __restrict__ feats3, const float* __restrict__ agg3ovf,
                        const float* __restrict__ iinv, const float* __restrict__ oinv,
                        const float* __restrict__ W0, const float* __restrict__ b0,
                        unsigned* __restrict__ hs, int n) {
    int t = blockIdx.x * blockDim.x + threadIdx.x;
    int i = t >> 5;
    if (i >= n) return;
    int q = t & 31;
    int deg = min(icnt[i], CAP);
    const unsigned short* row = eidx + i * CAP;
    float a0 = 0.f, a1 = 0.f, a2 = 0.f;
    for (int k = q; k < deg; k += 32) {
        int s = row[k];
        a0 += feats3[s * 3 + 0];
        a1 += feats3[s * 3 + 1];
        a2 += feats3[s * 3 + 2];
    }
    #pragma unroll
    for (int m = 1; m <= 16; m <<= 1) {
        a0 += __shfl_xor(a0, m);
        a1 += __shfl_xor(a1, m);
        a2 += __shfl_xor(a2, m);
    }
    a0 += agg3ovf[i * 3 + 0];
    a1 += agg3ovf[i * 3 + 1];
    a2 += agg3ovf[i * 3 + 2];
    float ii = iinv[i], oi = oinv[i];
    a0 *= ii; a1 *= ii; a2 *= ii;
    int j0 = q * 4;
    float4 w0r = *(const float4*)&W0[0 * DIM + j0];
    float4 w1r = *(const float4*)&W0[1 * DIM + j0];
    float4 w2r = *(const float4*)&W0[2 * DIM + j0];
    float4 bb  = *(const float4*)&b0[j0];
    float v0 = a0 * w0r.x + a1 * w1r.x + a2 * w2r.x + bb.x;
    float v1 = a0 * w0r.y + a1 * w1r.y + a2 * w2r.y + bb.y;
    float v2 = a0 * w0r.z + a1 * w1r.z + a2 * w2r.z + bb.z;
    float v3 = a0 * w0r.w + a1 * w1r.w + a2 * w2r.w + bb.w;
    v0 = v0 > 0.f ? v0 : NEG_SLOPE * v0;
    v1 = v1 > 0.f ? v1 : NEG_SLOPE * v1;
    v2 = v2 > 0.f ? v2 : NEG_SLOPE * v2;
    v3 = v3 > 0.f ? v3 : NEG_SLOPE * v3;
    ((uint2*)hs)[i * 32 + q] = make_uint2(f2b_rne2(v0 * oi, v1 * oi),
                                          f2b_rne2(v2 * oi, v3 * oi));
}

// ---------------- layer-2 aggregation: bucket gather, 32 threads/node ----------------
__global__ void k_gather128(const int* __restrict__ icnt, const unsigned short* __restrict__ eidx,
                            const unsigned* __restrict__ hs, float* __restrict__ out, int n) {
    int t = blockIdx.x * blockDim.x + threadIdx.x;
    int i = t >> 5;
    if (i >= n) return;
    int q = t & 31;
    int deg = min(icnt[i], CAP);
    const unsigned short* row = eidx + i * CAP;
    const uint2* hs2 = (const uint2*)hs;
    float a0 = 0.f, a1 = 0.f, a2 = 0.f, a3 = 0.f;
    int k = 0;
    for (; k + 2 <= deg; k += 2) {
        int s0 = row[k], s1 = row[k + 1];
        uint2 u0 = hs2[s0 * 32 + q];
        uint2 u1 = hs2[s1 * 32 + q];
        a0 += b2f_lo(u0.x) + b2f_lo(u1.x);
        a1 += b2f_hi(u0.x) + b2f_hi(u1.x);
        a2 += b2f_lo(u0.y) + b2f_lo(u1.y);
        a3 += b2f_hi(u0.y) + b2f_hi(u1.y);
    }
    if (k < deg) {
        int s = row[k];
        uint2 u = hs2[s * 32 + q];
        a0 += b2f_lo(u.x); a1 += b2f_hi(u.x);
        a2 += b2f_lo(u.y); a3 += b2f_hi(u.y);
    }
    ((float4*)out)[i * 32 + q] = make_float4(a0, a1, a2, a3);
}

// ---------------- layer-2 overflow edges: atomic add into out ----------------
__global__ void k_overflow(const int* __restrict__ ovf_cnt, const int2* __restrict__ ovf,
                           const unsigned* __restrict__ hs, float* __restrict__ out) {
    int g = blockIdx.x * blockDim.x + threadIdx.x;
    int entry = g >> 5, q = g & 31;
    int cnt = min(*ovf_cnt, OVF_MAX);
    if (entry >= cnt) return;
    int2 e = ovf[entry];                       // (dst, src)
    uint2 u = ((const uint2*)hs)[e.y * 32 + q];
    float* o = out + (size_t)e.x * DIM + q * 4;
    atomicAdd(o + 0, b2f_lo(u.x));
    atomicAdd(o + 1, b2f_hi(u.x));
    atomicAdd(o + 2, b2f_lo(u.y));
    atomicAdd(o + 3, b2f_hi(u.y));
}

// ---------------- final: out = (out * iinv) @ W1 + b1 ----------------
// 1024 threads, 256 nodes/block (grid 196 <= 256 CUs, one round).
// LDS: W1 only, padded stride 132 (w-reads 512B-contiguous per wave, conflict-free).
// A read from global: 32 row-sharing lanes are within one wave -> broadcast; in-place
// safe because those same lanes write only after all their reads (lockstep).
#define FB_NODES 256
#define SW_LD 132
__global__ __launch_bounds__(1024, 4) void k_final(const float* __restrict__ iinv,
                                                   const float* __restrict__ W1,
                                                   const float* __restrict__ b1,
                                                   float* __restrict__ out, int n) {
    __shared__ float sW[DIM * SW_LD];      // 67.6 KB
    int tid = threadIdx.x;
    for (int idx = tid; idx < DIM * DIM / 4; idx += 1024) {
        int r = idx >> 5, c4 = idx & 31;
        float4 v = ((const float4*)W1)[idx];
        *(float4*)&sW[r * SW_LD + c4 * 4] = v;
    }
    int cg = tid & 31;                     // cols cg*4 .. cg*4+3
    int ng = tid >> 5;                     // rows ng*8 .. ng*8+7
    int row0 = blockIdx.x * FB_NODES + ng * 8;
    float4 bb = *(const float4*)&b1[cg * 4];

    float acc[8][4];
    #pragma unroll
    for (int i = 0; i < 8; ++i)
        #pragma unroll
        for (int j = 0; j < 4; ++j) acc[i][j] = 0.f;

    __syncthreads();

    const float4* outf4 = (const float4*)out;
    for (int k4 = 0; k4 < 32; ++k4) {
        float4 a[8];
        #pragma unroll
        for (int i = 0; i < 8; ++i) {
            int r = min(row0 + i, n - 1);          // clamped read; store is guarded
            a[i] = outf4[(size_t)r * 32 + k4];
        }
        #pragma unroll
        for (int kk = 0; kk < 4; ++kk) {
            float4 w = *(const float4*)&sW[(k4 * 4 + kk) * SW_LD + cg * 4];
            #pragma unroll
            for (int i = 0; i < 8; ++i) {
                float av = (kk == 0) ? a[i].x : (kk == 1) ? a[i].y : (kk == 2) ? a[i].z : a[i].w;
                acc[i][0] += av * w.x;
                acc[i][1] += av * w.y;
                acc[i][2] += av * w.z;
                acc[i][3] += av * w.w;
            }
        }
    }

    #pragma unroll
    for (int i = 0; i < 8; ++i) {
        int r = row0 + i;
        if (r < n) {
            float ii = iinv[r];
            float4 o;
            o.x = acc[i][0] * ii + bb.x;
            o.y = acc[i][1] * ii + bb.y;
            o.z = acc[i][2] * ii + bb.z;
            o.w = acc[i][3] * ii + bb.w;
            ((float4*)out)[(size_t)r * 32 + cg] = o;
        }
    }
}

// ---------------- launch ----------------
extern "C" void kernel_launch(void* const* d_in, const int* in_sizes, int n_in,
                              void* d_out, int out_size, void* d_ws, size_t ws_size,
                              hipStream_t stream) {
    const int*   src  = (const int*)d_in[0];
    const int*   dst  = (const int*)d_in[1];
    const float* weight = (const float*)d_in[2];
    const int*   sig  = (const int*)d_in[3];
    const float* emb  = (const float*)d_in[4];
    const float* W0   = (const float*)d_in[5];
    const float* b0   = (const float*)d_in[6];
    const float* W1   = (const float*)d_in[7];
    const float* b1   = (const float*)d_in[8];
    float* out = (float*)d_out;

    // ---- workspace layout (4B words); zeroed buffers first ----
    int*   icnt    = (int*)d_ws;                          // @0        50000 (memset)
    int*   ovf_cnt = icnt + N_NODES;                      // @50000    8     (memset)
    float* agg3ovf = (float*)(ovf_cnt + 8);               // @50008    150000 (memset)
    int2*  ovf     = (int2*)(agg3ovf + 3 * N_NODES);      // @200008   4096 int2 (byte %8==0)
    float* oinv    = (float*)(ovf + OVF_MAX);             // @208200   50000
    float* iinv    = oinv + N_NODES;                      // @258200   50000
    float* feats3  = iinv + N_NODES;                      // @308200   150000
    int*   partial = (int*)(feats3 + 3 * N_NODES);        // @458200   3203072
    unsigned short* eidx = (unsigned short*)(partial + (size_t)NR * SLICES * RNODES);
    unsigned* hs   = (unsigned*)(eidx + (size_t)N_NODES * CAP);     // (byte %8==0)

    hipMemsetAsync(d_ws, 0, (size_t)(N_NODES + 8 + 3 * N_NODES) * 4, stream);

    k_fillbucket<<<(N_EDGES / 2 + 255) / 256, 256, 0, stream>>>(src, dst, icnt, eidx,
                                                                ovf_cnt, ovf, N_EDGES / 2);
    k_hist<<<NR * SLICES, 256, 0, stream>>>(src, partial);
    k_prep<<<(N_NODES + 255) / 256, 256, 0, stream>>>(weight, sig, emb, partial, icnt,
                                                      oinv, iinv, feats3, N_NODES);
    k_ovf3<<<(OVF_MAX + 255) / 256, 256, 0, stream>>>(ovf_cnt, ovf, feats3, agg3ovf);
    k_aggl1<<<(N_NODES * 32 + 255) / 256, 256, 0, stream>>>(icnt, eidx, feats3, agg3ovf,
                                                            iinv, oinv, W0, b0, hs, N_NODES);
    k_gather128<<<((N_NODES * 32) + 255) / 256, 256, 0, stream>>>(icnt, eidx, hs, out, N_NODES);
    k_overflow<<<(OVF_MAX * 32) / 256, 256, 0, stream>>>(ovf_cnt, ovf, hs, out);
    k_final<<<(N_NODES + FB_NODES - 1) / FB_NODES, 1024, 0, stream>>>(iinv, W1, b1, out, N_NODES);
}